// Round 1
// baseline (193.121 us; speedup 1.0000x reference)
//
#include <hip/hip_runtime.h>
#include <cstdint>

// ---------------------------------------------------------------------------
// MXFP linear w/ MSD(NAF) truncation.
//
// Reduction: x_q = sgn*mx*2^(ex-3), w_q = sgn*mw*2^(ew-3), mx,mw in [8,15].
// trunc(prod, eff) == sgn * R_q(2*mx*mw, clamp(eff,0,10)) * 2^(ex+ew-7)
// where R_q = NAF truncation of q=2p: x_h=p, s=3p, np=s&~p, nn=p&~s,
// drop = max(width(np|nn)-effc, 0), r = (np&keep)-(nn&keep).
// Scales fold exactly: fxs = sgn_x*x_s*2^ex, fws = sgn_w*w_s*2^(ew-7);
// contribution = (float)r * fxs * fws, accumulated over K, + bias.
// eff = 14 - (e_max(n,o) - floor(lx(n,b)+lw(o,b))) - d(n,b,i).
// ---------------------------------------------------------------------------

#define NN 128
#define KF 1024
#define OF 512
#define NB 32

__device__ __forceinline__ float quant_elem(float xn) {
    float a = fabsf(xn);
    if (!(a > 0.f)) return 0.f;
    float e = floorf(log2f(fmaxf(a, 1e-45f)));
    float step = exp2f(e - 3.f);
    return rintf(xn / step) * step;   // rintf = round-half-even, matches jnp.round
}

// blocks [0,512): x-quant.  [512,2560): w-quant.  [2560,2816): out = bias.
__global__ __launch_bounds__(256) void prep_kernel(
    const float* __restrict__ x, const float* __restrict__ w,
    const float* __restrict__ bias, float* __restrict__ out,
    uint2* __restrict__ xaT, uint2* __restrict__ wB,
    float* __restrict__ lxT, float* __restrict__ lw) {
  int bid = blockIdx.x;
  if (bid < 512) {
    int eid = bid * 256 + (int)threadIdx.x;      // 0..131071
    int n = eid >> 10, k = eid & 1023;
    float xv = x[eid];
    float m = fabsf(xv);
    #pragma unroll
    for (int s = 1; s < 32; s <<= 1) m = fmaxf(m, __shfl_xor(m, s, 32));
    float scale = fmaxf(m, 1e-30f);
    float xq = quant_elem(xv / scale);
    int mx = 0, ee = 0;
    if (xq != 0.f) {
      int ke; float fr = frexpf(fabsf(xq), &ke);
      mx = (int)rintf(fr * 16.f);                // in [8,15] (frexp normalizes 16->8)
      ee = ke - 1;
    }
    int e_i = mx ? ee : -1000000;
    int em = e_i;
    #pragma unroll
    for (int s = 1; s < 32; s <<= 1) em = max(em, __shfl_xor(em, s, 32));
    int d = mx ? min(em - ee, 63) : 63;          // d>=14 is always masked; clamp ok
    float fxs = mx ? copysignf(ldexpf(scale, ee), xq) : 0.f;
    xaT[k * NN + n] = make_uint2(__float_as_uint(fxs),
                                 (uint32_t)mx | ((uint32_t)d << 8));
    if ((threadIdx.x & 31) == 0) lxT[(k >> 5) * NN + n] = log2f(scale);
  } else if (bid < 2560) {
    int eid = (bid - 512) * 256 + (int)threadIdx.x;   // 0..524287
    int o = eid >> 10, k = eid & 1023;
    float wv = w[eid];
    float m = fabsf(wv);
    #pragma unroll
    for (int s = 1; s < 32; s <<= 1) m = fmaxf(m, __shfl_xor(m, s, 32));
    float scale = fmaxf(m, 1e-30f);
    float wq = quant_elem(wv / scale);
    int mw = 0, ee = 0;
    if (wq != 0.f) {
      int ke; float fr = frexpf(fabsf(wq), &ke);
      mw = (int)rintf(fr * 16.f);
      ee = ke - 1;
    }
    float fws = mw ? copysignf(ldexpf(scale, ee - 7), wq) : 0.f;
    wB[eid] = make_uint2(__float_as_uint(fws),
                         (uint32_t)mw | ((uint32_t)(3 * mw) << 16));
    if ((threadIdx.x & 31) == 0) lw[o * NB + (k >> 5)] = log2f(scale);
  } else {
    int gid = (bid - 2560) * 256 + (int)threadIdx.x;  // 0..65535
    out[gid] = bias[gid & (OF - 1)];
  }
}

__global__ __launch_bounds__(256) void emax_kernel(
    const float* __restrict__ lxT, const float* __restrict__ lw,
    float* __restrict__ emaxT) {
  int gid = blockIdx.x * 256 + (int)threadIdx.x;   // 65536
  int n = gid & (NN - 1), o = gid >> 7;
  float m = -1e30f;
  #pragma unroll
  for (int b = 0; b < NB; ++b)
    m = fmaxf(m, floorf(lxT[b * NN + n] + lw[o * NB + b]));
  emaxT[o * NN + n] = m;
}

// grid 4096 x 64 threads (1 wave/wg so o is provably uniform -> s_load for w).
// bid: kc = bid&31 (K chunk of 32 = one 32-block), ng = (bid>>5)&1, oct = bid>>6.
__global__ __launch_bounds__(64) void main_kernel(
    const uint2* __restrict__ xaT, const uint2* __restrict__ wB,
    const float* __restrict__ lxT, const float* __restrict__ lw,
    const float* __restrict__ emaxT, float* __restrict__ out) {
  int bid = blockIdx.x;
  int kc = bid & 31, ng = (bid >> 5) & 1, oct = bid >> 6;
  int lane = (int)threadIdx.x;
  int n = ng * 64 + lane;
  int o0 = oct * 8;

  float acc[8], bme[8];
  #pragma unroll
  for (int j = 0; j < 8; ++j) {
    acc[j] = 0.f;
    bme[j] = 14.f - emaxT[(o0 + j) * NN + n];
  }

  int b = kc;                       // this wave's single 32-wide block
  float lxv = lxT[b * NN + n];
  int budget[8];
  #pragma unroll
  for (int j = 0; j < 8; ++j)
    budget[j] = (int)(bme[j] + floorf(lxv + lw[(o0 + j) * NB + b]));

  int k0 = kc * 32;
  #pragma unroll 4
  for (int kk = 0; kk < 32; ++kk) {
    int k = k0 + kk;
    uint2 xv = xaT[k * NN + n];
    float fxs = __uint_as_float(xv.x);
    int mx = (int)(xv.y & 255u);
    int di = (int)(xv.y >> 8);
    #pragma unroll
    for (int j = 0; j < 8; ++j) {
      uint2 wv = wB[(o0 + j) * KF + k];      // uniform address -> scalar load
      float fws = __uint_as_float(wv.x);
      int mw  = (int)(wv.y & 0xFFFFu);
      int mw3 = (int)(wv.y >> 16);
      int p  = __mul24(mx, mw);              // p = mx*mw   (q = 2p)
      int s3 = __mul24(mx, mw3);             // s3 = 3p
      int t  = s3 & p;
      unsigned np = (unsigned)(s3 ^ t);      // q-NAF positive digits
      unsigned nn = (unsigned)(p ^ t);       // q-NAF negative digits
      int z = __clz(s3 ^ p);                 // 32 - width(np|nn); __clz(0)=32
      int eff  = budget[j] - di;
      int effc = min(max(eff, 0), 10);       // width(q-NAF) <= 10
      int drop = max(32 - z - effc, 0);      // <= 10
      unsigned keep = 0xFFFFFFFFu << drop;
      int r = (int)(np & keep) - (int)(nn & keep);
      acc[j] = fmaf((float)r * fxs, fws, acc[j]);
    }
  }
  #pragma unroll
  for (int j = 0; j < 8; ++j)
    unsafeAtomicAdd(&out[n * OF + o0 + j], acc[j]);
}

extern "C" void kernel_launch(void* const* d_in, const int* in_sizes, int n_in,
                              void* d_out, int out_size, void* d_ws, size_t ws_size,
                              hipStream_t stream) {
  const float* x    = (const float*)d_in[0];
  const float* w    = (const float*)d_in[1];
  const float* bias = (const float*)d_in[2];
  float* out = (float*)d_out;
  char* ws = (char*)d_ws;
  // workspace layout (bytes): xaT 1MB | wB 4MB | lxT 16KB | lw 64KB | emaxT 256KB
  uint2* xaT   = (uint2*)(ws);
  uint2* wB    = (uint2*)(ws + 1048576);
  float* lxT   = (float*)(ws + 5242880);
  float* lw    = (float*)(ws + 5259264);
  float* emaxT = (float*)(ws + 5324800);

  prep_kernel<<<2816, 256, 0, stream>>>(x, w, bias, out, xaT, wB, lxT, lw);
  emax_kernel<<<256, 256, 0, stream>>>(lxT, lw, emaxT);
  main_kernel<<<4096, 64, 0, stream>>>(xaT, wB, lxT, lw, emaxT, out);
}